// Round 6
// baseline (79.755 us; speedup 1.0000x reference)
//
#include <hip/hip_runtime.h>

#define BB 4
#define CIN 256
#define COUT 256
#define HH 64
#define WW 64
#define KK 9
#define OC2 18
#define KTOT (CIN * KK)        // 2304
#define NSTAGE 18              // 128-k stages (main kernel)

typedef __attribute__((ext_vector_type(8))) _Float16 h8;
typedef __attribute__((ext_vector_type(4))) float f32x4;

static __device__ __forceinline__ h8 splat_pk(unsigned pk) {
    union { unsigned u[4]; h8 h; } s;
    s.u[0] = pk; s.u[1] = pk; s.u[2] = pk; s.u[3] = pk;
    return s.h;
}

// ---------------------------------------------------------------------------
// Kernel 1 (fused prework): transpose x -> xT (1024 blocks), pack dcn_w -> bp
// (288 blocks), pack offset_w -> bow (36 blocks). One launch, 1348 blocks.
// ---------------------------------------------------------------------------
__global__ __launch_bounds__(256) void prework_kernel(
    const float* __restrict__ x, const float* __restrict__ ow,
    const float* __restrict__ dw,
    _Float16* __restrict__ xT, _Float16* __restrict__ bp,
    _Float16* __restrict__ bow)
{
    const int bid = blockIdx.x;
    const int t = threadIdx.x;
    if (bid < 1024) {
        // ---- transpose chunk: (b, y, 64-channel group) ----
        const int b = bid >> 8, y = (bid >> 2) & 63, c0 = (bid & 3) * 64;
        __shared__ float tile[64][65];
#pragma unroll
        for (int r = 0; r < 16; ++r) {
            int idx = r * 256 + t;
            int c = idx >> 6, w = idx & 63;
            tile[c][w] = x[(((size_t)(b * CIN + c0 + c)) << 12) + (y << 6) + w];
        }
        __syncthreads();
#pragma unroll
        for (int half = 0; half < 2; ++half) {
            int cg_l = (t >> 6) + 4 * half, xx = t & 63;
            union { _Float16 h[8]; uint4 q; } u;
#pragma unroll
            for (int j = 0; j < 8; ++j) u.h[j] = (_Float16)tile[cg_l * 8 + j][xx];
            int cg = (c0 >> 3) + cg_l;
            *(uint4*)&xT[((((size_t)(b * 32 + cg)) << 12) + (y << 6) + xx) * 8] = u.q;
        }
    } else if (bid < 1312) {
        // ---- pack dcn_w: word wid = (T*16 + cotile)*64 + lane (T = 32-k step) ----
        int wid = (bid - 1024) * 256 + t;
        int T = wid >> 10;
        int r = wid & 1023;
        int cotile = r >> 6, lane = r & 63;
        int co = cotile * 16 + (lane & 15);
        int kbase = T * 32 + ((lane >> 4) & 3) * 8;
        union { _Float16 h[8]; uint4 q; } u;
#pragma unroll
        for (int j = 0; j < 8; ++j) {
            int k = kbase + j;
            int c = k & 255, kk = k >> 8;
            u.h[j] = (_Float16)dw[co * KTOT + c * KK + kk];
        }
        *(uint4*)&bp[(size_t)wid * 8] = u.q;
    } else {
        // ---- pack offset_w (oc padded 18->32): wid = (T*2+nj)*64+lane ----
        int wid = (bid - 1312) * 256 + t;
        int T = wid >> 7;
        int r = wid & 127;
        int lane = r & 63;
        int oc = ((r >> 6) << 4) + (lane & 15);
        int kbase = T * 32 + ((lane >> 4) & 3) * 8;
        union { _Float16 h[8]; uint4 q; } u;
#pragma unroll
        for (int j = 0; j < 8; ++j) {
            int k = kbase + j;
            int c = k & 255, kk = k >> 8;
            u.h[j] = (oc < OC2) ? (_Float16)ow[oc * KTOT + c * KK + kk] : (_Float16)0.f;
        }
        *(uint4*)&bow[(size_t)wid * 8] = u.q;
    }
}

// ---------------------------------------------------------------------------
// Kernel 2: offset conv MFMA GEMM, split-K=2, each half writes its own fp32
// partial buffer (no atomics; main kernel sums both halves + bias).
// ---------------------------------------------------------------------------
__global__ __launch_bounds__(256) void offset_mfma_kernel(
    const _Float16* __restrict__ xT, const _Float16* __restrict__ bow,
    float* __restrict__ opart)
{
    const int bid = blockIdx.x;
    const int m_blk = bid >> 1, kh = bid & 1;
    const int b = m_blk >> 6;
    const int pxbase = (m_blk & 63) * 64;
    const int tid = threadIdx.x;
    const int lane = tid & 63, wv = tid >> 6;
    const int pin = lane & 15, kg = lane >> 4;

    __shared__ __align__(16) _Float16 Asl[2][2048];

    const _Float16* xb = xT + ((size_t)b << 20);
    const int pxl = pxbase + (wv << 4) + pin;
    const int py = pxl >> 6, px = pxl & 63;

    auto GLOAD = [&](int st, h8& R) {
        int kk = st >> 3;
        int ky = kk / 3, kx = kk - 3 * (kk / 3);
        int cg = (st & 7) * 4 + kg;
        int yy = py + ky - 1, xx = px + kx - 1;
        h8 v = {0, 0, 0, 0, 0, 0, 0, 0};
        if ((unsigned)yy < HH && (unsigned)xx < WW)
            v = *(const h8*)(xb + (((size_t)cg << 12) + (yy << 6) + xx) * 8);
        R = v;
    };
    auto BLOAD = [&](int st, uint4* br) {
#pragma unroll
        for (int nj = 0; nj < 2; ++nj)
            br[nj] = *(const uint4*)&bow[(size_t)(((st << 1) + nj) * 64 + lane) * 8];
    };

    f32x4 acc[2];
    {
        f32x4 z = {0.f, 0.f, 0.f, 0.f};
        acc[0] = z; acc[1] = z;
    }

    const int t0 = kh * 36;
    h8 RA, RB;
    uint4 bregA[2], bregB[2];

    GLOAD(t0, RA);
    GLOAD(t0 + 1, RB);
    BLOAD(t0, bregA);
    *(h8*)&Asl[0][tid * 8] = RA;
    __syncthreads();

    for (int tt = 0; tt < 36; tt += 2) {
        int st = t0 + tt;
        if (tt + 2 < 36) GLOAD(st + 2, RA);
        BLOAD(st + 1, bregB);
        {
            h8 a = *(const h8*)&Asl[0][tid * 8];
            union { uint4 q; h8 h; } bb;
#pragma unroll
            for (int nj = 0; nj < 2; ++nj) {
                bb.q = bregA[nj];
                acc[nj] = __builtin_amdgcn_mfma_f32_16x16x32_f16(a, bb.h, acc[nj], 0, 0, 0);
            }
        }
        *(h8*)&Asl[1][tid * 8] = RB;
        __syncthreads();
        if (tt + 3 < 36) GLOAD(st + 3, RB);
        if (tt + 2 < 36) BLOAD(st + 2, bregA);
        {
            h8 a = *(const h8*)&Asl[1][tid * 8];
            union { uint4 q; h8 h; } bb;
#pragma unroll
            for (int nj = 0; nj < 2; ++nj) {
                bb.q = bregB[nj];
                acc[nj] = __builtin_amdgcn_mfma_f32_16x16x32_f16(a, bb.h, acc[nj], 0, 0, 0);
            }
        }
        if (tt + 2 < 36) *(h8*)&Asl[0][tid * 8] = RA;
        __syncthreads();
    }

    const int pxb = pxbase + (wv << 4) + kg * 4;
#pragma unroll
    for (int nj = 0; nj < 2; ++nj) {
        int oc = nj * 16 + pin;
        if (oc < OC2) {
            float4 o;
            o.x = acc[nj][0]; o.y = acc[nj][1];
            o.z = acc[nj][2]; o.w = acc[nj][3];
            *(float4*)&opart[(((size_t)((kh * BB + b) * OC2 + oc)) << 12) + pxb] = o;
        }
    }
}

// ---------------------------------------------------------------------------
// Kernel 3: fused bilinear-gather + MFMA implicit GEMM (fp16), v5.
// 1024 blocks (32px x 128co), 512 thr = 8 waves (1M x 8N: wave 32px x 16co).
// BK=128 -> 18 stages/barriers. Each thread gathers exactly one A word/stage
// (px = tid&31, cgL = tid>>5). Stateless corner addressing from LDS table.
// A-LDS index keeps both ds_write and ds_read lane-contiguous (0 conflicts).
// ---------------------------------------------------------------------------
__global__ __launch_bounds__(512, 4) void dcn_mfma_kernel(
    const _Float16* __restrict__ xT, const float* __restrict__ opart,
    const float* __restrict__ ob, const _Float16* __restrict__ bp,
    const float* __restrict__ db, float* __restrict__ out)
{
    int P = blockIdx.x;
    int L = (P & 7) * 128 + (P >> 3);     // XCD swizzle (1024 % 8 == 0, bijective)
    const int m_blk = L >> 1, n0 = L & 1;
    const int b = m_blk >> 7;
    const int rowbase = (m_blk & 127) * 32;

    const int tid = threadIdx.x;
    const int lane = tid & 63;
    const int wv = tid >> 6;              // 0..7 = N-slice
    const int kg = lane >> 4, pin = lane & 15;

    // gather role: one A word per thread per stage
    const int g_px = tid & 31;            // px within tile
    const int g_cgL = tid >> 5;           // 0..15: channel-group within 128-k stage
    const int g_ebase = g_px * 9;
    // A-LDS word index for (px=g_px, cgL=g_cgL):
    const int g_widx = (g_cgL >> 2) * 128 + ((g_px >> 4) << 6) + (g_cgL & 3) * 16 + (g_px & 15);

    __shared__ __align__(16) _Float16 Asl[2][4096];  // 512 words x 16B per buf
    __shared__ __align__(16) uint4 tw4[288];         // dup-packed fp16 bilinear weights
    __shared__ __align__(16) uint2 tih[288];         // 4 packed u16 pixel indices

    // ---- bilinear table: 32 px x 9 taps (sums split-K offset partials + bias) ----
    const float* op0 = opart + (((size_t)(b * OC2)) << 12);
    const float* op1 = opart + (((size_t)((BB + b) * OC2)) << 12);
    if (tid < 288) {
        int e = tid;
        int p = e / 9, kk = e - (e / 9) * 9;
        int pxl = rowbase + p;
        int y = pxl >> 6, xx = pxl & 63;
        float dy = op0[((size_t)(2 * kk) << 12) + pxl]
                 + op1[((size_t)(2 * kk) << 12) + pxl] + ob[2 * kk];
        float dx = op0[((size_t)(2 * kk + 1) << 12) + pxl]
                 + op1[((size_t)(2 * kk + 1) << 12) + pxl] + ob[2 * kk + 1];
        int ky = kk / 3, kx = kk - 3 * (kk / 3);
        float sy = (float)(y - 1 + ky) + dy;
        float sx = (float)(xx - 1 + kx) + dx;
        float fy = floorf(sy), fx = floorf(sx);
        int y0 = (int)fy, x0 = (int)fx;
        float wy1 = sy - fy, wx1 = sx - fx;
        float wy0 = 1.f - wy1, wx0 = 1.f - wx1;
        bool vy0 = (unsigned)y0 < HH, vy1 = (unsigned)(y0 + 1) < HH;
        bool vx0 = (unsigned)x0 < WW, vx1 = (unsigned)(x0 + 1) < WW;
        _Float16 w00 = (_Float16)((vy0 && vx0) ? wy0 * wx0 : 0.f);
        _Float16 w01 = (_Float16)((vy0 && vx1) ? wy0 * wx1 : 0.f);
        _Float16 w10 = (_Float16)((vy1 && vx0) ? wy1 * wx0 : 0.f);
        _Float16 w11 = (_Float16)((vy1 && vx1) ? wy1 * wx1 : 0.f);
        union { _Float16 h[2]; unsigned u; } pk;
        uint4 W;
        pk.h[0] = w00; pk.h[1] = w00; W.x = pk.u;
        pk.h[0] = w01; pk.h[1] = w01; W.y = pk.u;
        pk.h[0] = w10; pk.h[1] = w10; W.z = pk.u;
        pk.h[0] = w11; pk.h[1] = w11; W.w = pk.u;
        tw4[e] = W;
        int y0c = min(max(y0, 0), HH - 1), y1c = min(max(y0 + 1, 0), HH - 1);
        int x0c = min(max(x0, 0), WW - 1), x1c = min(max(x0 + 1, 0), WW - 1);
        unsigned i00 = (unsigned)((y0c << 6) + x0c);
        unsigned i01 = (unsigned)((y0c << 6) + x1c);
        unsigned i10 = (unsigned)((y1c << 6) + x0c);
        unsigned i11 = (unsigned)((y1c << 6) + x1c);
        tih[e] = make_uint2(i00 | (i01 << 16), i10 | (i11 << 16));
    }
    __syncthreads();

    const char* xbyte = (const char*)(xT + ((size_t)b << 20));   // wave-uniform -> SGPR base

    // issue 4 corner loads for stage st (stateless: table + kk-derived base)
    auto GLOAD = [&](int st, h8& c00, h8& c01, h8& c10, h8& c11) {
        int kk = st >> 1;
        int e = g_ebase + kk;
        uint2 ij = tih[e];
        unsigned boff = ((unsigned)((st & 1) * 16 + g_cgL)) << 16;  // 32-bit voffset base
        c00 = *(const h8*)(xbyte + (boff + ((ij.x & 0xFFFFu) << 4)));
        c01 = *(const h8*)(xbyte + (boff + ((ij.x >> 16)     << 4)));
        c10 = *(const h8*)(xbyte + (boff + ((ij.y & 0xFFFFu) << 4)));
        c11 = *(const h8*)(xbyte + (boff + ((ij.y >> 16)     << 4)));
    };
    // consume: weights re-read from LDS table; write A word to buf
    auto GCONSUME = [&](int st, int buf, h8 c00, h8 c01, h8 c10, h8 c11) {
        int e = g_ebase + (st >> 1);
        uint4 wq = tw4[e];
        h8 v = c00 * splat_pk(wq.x);
        v += c01 * splat_pk(wq.y);
        v += c10 * splat_pk(wq.z);
        v += c11 * splat_pk(wq.w);
        *(h8*)&Asl[buf][g_widx * 8] = v;
    };
    // B: 4 words per thread per stage (ks = 0..3), coalesced from packed global
    auto BLOAD = [&](int st, uint4* br) {
#pragma unroll
        for (int ks = 0; ks < 4; ++ks) {
            size_t word = ((size_t)((st * 4 + ks) * 16 + n0 * 8 + wv)) * 64 + lane;
            br[ks] = *(const uint4*)&bp[word * 8];
        }
    };

    f32x4 acc[2];
    {
        f32x4 z = {0.f, 0.f, 0.f, 0.f};
        acc[0] = z; acc[1] = z;
    }

    h8 C0, C1, C2, C3;
    uint4 breg[4], bnext[4];

    GLOAD(0, C0, C1, C2, C3);
    BLOAD(0, breg);
    GCONSUME(0, 0, C0, C1, C2, C3);
    __syncthreads();

#pragma unroll 2
    for (int st = 0; st < NSTAGE; ++st) {
        const int cur = st & 1;
        if (st + 1 < NSTAGE) {
            GLOAD(st + 1, C0, C1, C2, C3);   // scattered loads in flight
            BLOAD(st + 1, bnext);            // coalesced loads in flight
        }
        // 8 ds_read_b128 (lane-contiguous) + 8 MFMA
#pragma unroll
        for (int ks = 0; ks < 4; ++ks) {
            h8 a0 = *(const h8*)&Asl[cur][(ks * 128 + lane) * 8];
            h8 a1 = *(const h8*)&Asl[cur][(ks * 128 + 64 + lane) * 8];
            union { uint4 q; h8 h; } bb; bb.q = breg[ks];
            acc[0] = __builtin_amdgcn_mfma_f32_16x16x32_f16(a0, bb.h, acc[0], 0, 0, 0);
            acc[1] = __builtin_amdgcn_mfma_f32_16x16x32_f16(a1, bb.h, acc[1], 0, 0, 0);
        }
        if (st + 1 < NSTAGE)
            GCONSUME(st + 1, cur ^ 1, C0, C1, C2, C3);  // vm-wait lands AFTER MFMAs
        __syncthreads();
#pragma unroll
        for (int i = 0; i < 4; ++i) breg[i] = bnext[i];
    }

    // ---- epilogue: col=lane&15 -> co, row=(lane>>4)*4+reg -> px ----
    const int co = n0 * 128 + wv * 16 + pin;
    const float bv = db[co];
    float* op = out + ((size_t)(b * COUT + co) << 12) + rowbase;
#pragma unroll
    for (int mi = 0; mi < 2; ++mi) {
        int pxoff = mi * 16 + kg * 4;
        float4 o;
        o.x = acc[mi][0] + bv;
        o.y = acc[mi][1] + bv;
        o.z = acc[mi][2] + bv;
        o.w = acc[mi][3] + bv;
        *(float4*)&op[pxoff] = o;
    }
}

// ---------------------------------------------------------------------------
extern "C" void kernel_launch(void* const* d_in, const int* in_sizes, int n_in,
                              void* d_out, int out_size, void* d_ws, size_t ws_size,
                              hipStream_t stream)
{
    const float* x  = (const float*)d_in[0];
    const float* ow = (const float*)d_in[1];
    const float* ob = (const float*)d_in[2];
    const float* dw = (const float*)d_in[3];
    const float* db = (const float*)d_in[4];
    float* out = (float*)d_out;

    // ws layout (bytes):
    // opart f32 [2][4][18][4096] = 2359296 | bp f16 1179648 | bow f16 147456 | xT f16 8388608
    char* wsp = (char*)d_ws;
    float*     opart = (float*)wsp;
    _Float16*  bp    = (_Float16*)(wsp + 2359296);
    _Float16*  bow   = (_Float16*)(wsp + 3538944);
    _Float16*  xT    = (_Float16*)(wsp + 3686400);

    hipLaunchKernelGGL(prework_kernel,     dim3(1348), dim3(256), 0, stream, x, ow, dw, xT, bp, bow);
    hipLaunchKernelGGL(offset_mfma_kernel, dim3(512),  dim3(256), 0, stream, xT, bow, opart);
    hipLaunchKernelGGL(dcn_mfma_kernel,    dim3(1024), dim3(512), 0, stream, xT, opart, ob, bp, db, out);
}

// Round 7
// 77.092 us; speedup vs baseline: 1.0345x; 1.0345x over previous
//
#include <hip/hip_runtime.h>

#define BB 4
#define CIN 256
#define COUT 256
#define HH 64
#define WW 64
#define KK 9
#define OC2 18
#define KTOT (CIN * KK)        // 2304
#define NSTAGE 18              // 128-k stages (main kernel)

typedef __attribute__((ext_vector_type(8))) _Float16 h8;
typedef __attribute__((ext_vector_type(4))) float f32x4;

static __device__ __forceinline__ h8 splat_pk(unsigned pk) {
    union { unsigned u[4]; h8 h; } s;
    s.u[0] = pk; s.u[1] = pk; s.u[2] = pk; s.u[3] = pk;
    return s.h;
}

// ---------------------------------------------------------------------------
// Kernel 1 (fused prework):
//   blocks 0..1023    : transpose x [B][C][H][W] f32 -> xT [B][px][256c] f16
//   blocks 1024..1311 : pack dcn_w -> bp fragments
//   blocks 1312..1347 : pack offset_w -> bow fragments (oc padded 18->32)
// ---------------------------------------------------------------------------
__global__ __launch_bounds__(256) void prework_kernel(
    const float* __restrict__ x, const float* __restrict__ ow,
    const float* __restrict__ dw,
    _Float16* __restrict__ xT, _Float16* __restrict__ bp,
    _Float16* __restrict__ bow)
{
    const int bid = blockIdx.x;
    const int t = threadIdx.x;
    if (bid < 1024) {
        // ---- transpose chunk: (b, y, 64-channel group) -> pixel-major ----
        const int b = bid >> 8, y = (bid >> 2) & 63, c0 = (bid & 3) * 64;
        __shared__ float tile[64][65];
#pragma unroll
        for (int r = 0; r < 16; ++r) {
            int idx = r * 256 + t;
            int c = idx >> 6, w = idx & 63;
            tile[c][w] = x[(((size_t)(b * CIN + c0 + c)) << 12) + (y << 6) + w];
        }
        __syncthreads();
        const int px = t >> 2;
#pragma unroll
        for (int half = 0; half < 2; ++half) {
            int cc = (t & 3) + half * 4;              // 8-ch chunk within c0 block
            union { _Float16 h[8]; uint4 q; } u;
#pragma unroll
            for (int j = 0; j < 8; ++j) u.h[j] = (_Float16)tile[cc * 8 + j][px];
            size_t el = (((size_t)(b << 12)) + (y << 6) + px) * 256 + c0 + cc * 8;
            *(uint4*)&xT[el] = u.q;
        }
    } else if (bid < 1312) {
        // ---- pack dcn_w: word wid = (T*16 + cotile)*64 + lane (T = 32-k step) ----
        int wid = (bid - 1024) * 256 + t;
        int T = wid >> 10;
        int r = wid & 1023;
        int cotile = r >> 6, lane = r & 63;
        int co = cotile * 16 + (lane & 15);
        int kbase = T * 32 + ((lane >> 4) & 3) * 8;
        union { _Float16 h[8]; uint4 q; } u;
#pragma unroll
        for (int j = 0; j < 8; ++j) {
            int k = kbase + j;
            int c = k & 255, kk = k >> 8;
            u.h[j] = (_Float16)dw[co * KTOT + c * KK + kk];
        }
        *(uint4*)&bp[(size_t)wid * 8] = u.q;
    } else {
        // ---- pack offset_w (oc padded 18->32): wid = (T*2+nj)*64+lane ----
        int wid = (bid - 1312) * 256 + t;
        int T = wid >> 7;
        int r = wid & 127;
        int lane = r & 63;
        int oc = ((r >> 6) << 4) + (lane & 15);
        int kbase = T * 32 + ((lane >> 4) & 3) * 8;
        union { _Float16 h[8]; uint4 q; } u;
#pragma unroll
        for (int j = 0; j < 8; ++j) {
            int k = kbase + j;
            int c = k & 255, kk = k >> 8;
            u.h[j] = (oc < OC2) ? (_Float16)ow[oc * KTOT + c * KK + kk] : (_Float16)0.f;
        }
        *(uint4*)&bow[(size_t)wid * 8] = u.q;
    }
}

// ---------------------------------------------------------------------------
// Kernel 2: offset conv MFMA GEMM, split-K=2, partial buffers (no atomics).
// Reads pixel-major xT: aligned taps, per-wave 16px x 64B contiguous chunks.
// ---------------------------------------------------------------------------
__global__ __launch_bounds__(256) void offset_mfma_kernel(
    const _Float16* __restrict__ xT, const _Float16* __restrict__ bow,
    float* __restrict__ opart)
{
    const int bid = blockIdx.x;
    const int m_blk = bid >> 1, kh = bid & 1;
    const int b = m_blk >> 6;
    const int pxbase = (m_blk & 63) * 64;
    const int tid = threadIdx.x;
    const int lane = tid & 63, wv = tid >> 6;
    const int pin = lane & 15, kg = lane >> 4;

    __shared__ __align__(16) _Float16 Asl[2][2048];

    const _Float16* xb = xT + ((size_t)b << 20);   // 4096 px * 256 ch
    const int pxl = pxbase + (wv << 4) + pin;
    const int py = pxl >> 6, px = pxl & 63;

    auto GLOAD = [&](int st, h8& R) {
        int kk = st >> 3;
        int ky = kk / 3, kx = kk - 3 * (kk / 3);
        int yy = py + ky - 1, xx = px + kx - 1;
        h8 v = {0, 0, 0, 0, 0, 0, 0, 0};
        if ((unsigned)yy < HH && (unsigned)xx < WW)
            v = *(const h8*)(xb + (((yy << 6) + xx) << 8) + (st & 7) * 32 + kg * 8);
        R = v;
    };
    auto BLOAD = [&](int st, uint4* br) {
#pragma unroll
        for (int nj = 0; nj < 2; ++nj)
            br[nj] = *(const uint4*)&bow[(size_t)(((st << 1) + nj) * 64 + lane) * 8];
    };

    f32x4 acc[2];
    {
        f32x4 z = {0.f, 0.f, 0.f, 0.f};
        acc[0] = z; acc[1] = z;
    }

    const int t0 = kh * 36;
    h8 RA, RB;
    uint4 bregA[2], bregB[2];

    GLOAD(t0, RA);
    GLOAD(t0 + 1, RB);
    BLOAD(t0, bregA);
    *(h8*)&Asl[0][tid * 8] = RA;
    __syncthreads();

    for (int tt = 0; tt < 36; tt += 2) {
        int st = t0 + tt;
        if (tt + 2 < 36) GLOAD(st + 2, RA);
        BLOAD(st + 1, bregB);
        {
            h8 a = *(const h8*)&Asl[0][tid * 8];
            union { uint4 q; h8 h; } bb;
#pragma unroll
            for (int nj = 0; nj < 2; ++nj) {
                bb.q = bregA[nj];
                acc[nj] = __builtin_amdgcn_mfma_f32_16x16x32_f16(a, bb.h, acc[nj], 0, 0, 0);
            }
        }
        *(h8*)&Asl[1][tid * 8] = RB;
        __syncthreads();
        if (tt + 3 < 36) GLOAD(st + 3, RB);
        if (tt + 2 < 36) BLOAD(st + 2, bregA);
        {
            h8 a = *(const h8*)&Asl[1][tid * 8];
            union { uint4 q; h8 h; } bb;
#pragma unroll
            for (int nj = 0; nj < 2; ++nj) {
                bb.q = bregB[nj];
                acc[nj] = __builtin_amdgcn_mfma_f32_16x16x32_f16(a, bb.h, acc[nj], 0, 0, 0);
            }
        }
        if (tt + 2 < 36) *(h8*)&Asl[0][tid * 8] = RA;
        __syncthreads();
    }

    const int pxb = pxbase + (wv << 4) + kg * 4;
#pragma unroll
    for (int nj = 0; nj < 2; ++nj) {
        int oc = nj * 16 + pin;
        if (oc < OC2) {
            float4 o;
            o.x = acc[nj][0]; o.y = acc[nj][1];
            o.z = acc[nj][2]; o.w = acc[nj][3];
            *(float4*)&opart[(((size_t)((kh * BB + b) * OC2 + oc)) << 12) + pxb] = o;
        }
    }
}

// ---------------------------------------------------------------------------
// Kernel 3: fused bilinear-gather + MFMA implicit GEMM (fp16), v6.
// 1024 blocks (32px x 128co), 512 thr = 8 waves (1M x 8N).
// Pixel-major gather: roles px = tid>>4, cg = tid&15 -> each corner-load
// instruction = 4 px x 256B contiguous (16 lines). 2-stage-deep A prefetch
// (reg sets E/F); 1-deep B prefetch; XOR-swizzled A-LDS (write & read).
// ---------------------------------------------------------------------------
__global__ __launch_bounds__(512, 4) void dcn_mfma_kernel(
    const _Float16* __restrict__ xT, const float* __restrict__ opart,
    const float* __restrict__ ob, const _Float16* __restrict__ bp,
    const float* __restrict__ db, float* __restrict__ out)
{
    int P = blockIdx.x;
    int L = (P & 7) * 128 + (P >> 3);     // XCD swizzle (1024 % 8 == 0, bijective)
    const int m_blk = L >> 1, n0 = L & 1;
    const int b = m_blk >> 7;
    const int rowbase = (m_blk & 127) * 32;

    const int tid = threadIdx.x;
    const int lane = tid & 63;
    const int wv = tid >> 6;              // 0..7 = N-slice
    const int kslice = lane >> 4, pxlo = lane & 15;

    // gather role: one A word (8 ch) per thread per stage
    const int g_px = tid >> 4;            // 0..31 px within tile
    const int g_cg = tid & 15;            // 8-ch chunk within 128-k stage
    const int g_ebase = g_px * 9;
    // swizzled A-LDS word index (2-way max on write, contiguous on read)
    const int g_widx = (g_cg >> 2) * 128 + ((g_px >> 4) << 6) + (g_cg & 3) * 16
                     + ((g_px & 15) ^ (g_cg & 7));

    __shared__ __align__(16) _Float16 Asl[2][4096];  // 8 KB per buf
    __shared__ __align__(8) uint2 twA[288];          // packed (w00,w01) fp16 dup-pairs
    __shared__ __align__(8) uint2 twB[288];          // packed (w10,w11)
    __shared__ __align__(8) uint2 tih[288];          // 4 packed u16 pixel indices

    // ---- bilinear table: 32 px x 9 taps (sums split-K offset partials + bias) ----
    const float* op0 = opart + (((size_t)(b * OC2)) << 12);
    const float* op1 = opart + (((size_t)((BB + b) * OC2)) << 12);
    if (tid < 288) {
        int e = tid;
        int p = e / 9, kk = e - (e / 9) * 9;
        int pxl = rowbase + p;
        int y = pxl >> 6, xx = pxl & 63;
        float dy = op0[((size_t)(2 * kk) << 12) + pxl]
                 + op1[((size_t)(2 * kk) << 12) + pxl] + ob[2 * kk];
        float dx = op0[((size_t)(2 * kk + 1) << 12) + pxl]
                 + op1[((size_t)(2 * kk + 1) << 12) + pxl] + ob[2 * kk + 1];
        int ky = kk / 3, kx = kk - 3 * (kk / 3);
        float sy = (float)(y - 1 + ky) + dy;
        float sx = (float)(xx - 1 + kx) + dx;
        float fy = floorf(sy), fx = floorf(sx);
        int y0 = (int)fy, x0 = (int)fx;
        float wy1 = sy - fy, wx1 = sx - fx;
        float wy0 = 1.f - wy1, wx0 = 1.f - wx1;
        bool vy0 = (unsigned)y0 < HH, vy1 = (unsigned)(y0 + 1) < HH;
        bool vx0 = (unsigned)x0 < WW, vx1 = (unsigned)(x0 + 1) < WW;
        _Float16 w00 = (_Float16)((vy0 && vx0) ? wy0 * wx0 : 0.f);
        _Float16 w01 = (_Float16)((vy0 && vx1) ? wy0 * wx1 : 0.f);
        _Float16 w10 = (_Float16)((vy1 && vx0) ? wy1 * wx0 : 0.f);
        _Float16 w11 = (_Float16)((vy1 && vx1) ? wy1 * wx1 : 0.f);
        union { _Float16 h[2]; unsigned u; } pk;
        uint2 WA, WB;
        pk.h[0] = w00; pk.h[1] = w00; WA.x = pk.u;
        pk.h[0] = w01; pk.h[1] = w01; WA.y = pk.u;
        pk.h[0] = w10; pk.h[1] = w10; WB.x = pk.u;
        pk.h[0] = w11; pk.h[1] = w11; WB.y = pk.u;
        twA[e] = WA;
        twB[e] = WB;
        int y0c = min(max(y0, 0), HH - 1), y1c = min(max(y0 + 1, 0), HH - 1);
        int x0c = min(max(x0, 0), WW - 1), x1c = min(max(x0 + 1, 0), WW - 1);
        unsigned i00 = (unsigned)((y0c << 6) + x0c);
        unsigned i01 = (unsigned)((y0c << 6) + x1c);
        unsigned i10 = (unsigned)((y1c << 6) + x0c);
        unsigned i11 = (unsigned)((y1c << 6) + x1c);
        tih[e] = make_uint2(i00 | (i01 << 16), i10 | (i11 << 16));
    }
    __syncthreads();

    const char* xbyte = (const char*)(xT + ((size_t)b << 20));  // uniform -> SGPR

    // issue 4 coalesced corner loads for stage st (pixel-major: pixidx*512+chb)
    auto GLOAD = [&](int st, h8& c00, h8& c01, h8& c10, h8& c11) {
        uint2 ij = tih[g_ebase + (st >> 1)];
        unsigned chb = (unsigned)((st & 1) * 256 + g_cg * 16);
        c00 = *(const h8*)(xbyte + (((ij.x & 0xFFFFu) << 9) + chb));
        c01 = *(const h8*)(xbyte + (((ij.x >> 16)     << 9) + chb));
        c10 = *(const h8*)(xbyte + (((ij.y & 0xFFFFu) << 9) + chb));
        c11 = *(const h8*)(xbyte + (((ij.y >> 16)     << 9) + chb));
    };
    // consume: bilinear combine + swizzled ds_write (vm-wait lands here, post-MFMA)
    auto GCONSUME = [&](int st, int buf, h8 c00, h8 c01, h8 c10, h8 c11) {
        int e = g_ebase + (st >> 1);
        uint2 wa = twA[e], wb = twB[e];
        h8 v = c00 * splat_pk(wa.x);
        v += c01 * splat_pk(wa.y);
        v += c10 * splat_pk(wb.x);
        v += c11 * splat_pk(wb.y);
        *(h8*)&Asl[buf][g_widx * 8] = v;
    };
    auto BLOAD = [&](int st, uint4* br) {
#pragma unroll
        for (int ks = 0; ks < 4; ++ks) {
            size_t word = ((size_t)((st * 4 + ks) * 16 + n0 * 8 + wv)) * 64 + lane;
            br[ks] = *(const uint4*)&bp[word * 8];
        }
    };

    f32x4 acc[2];
    {
        f32x4 z = {0.f, 0.f, 0.f, 0.f};
        acc[0] = z; acc[1] = z;
    }

    auto MFMA8 = [&](int buf, uint4* br) {
        __builtin_amdgcn_s_setprio(1);
#pragma unroll
        for (int ks = 0; ks < 4; ++ks) {
            int w0 = ks * 128 + kslice * 16 + (pxlo ^ ((ks * 4 + kslice) & 7));
            h8 a0 = *(const h8*)&Asl[buf][w0 * 8];
            h8 a1 = *(const h8*)&Asl[buf][(w0 + 64) * 8];
            union { uint4 q; h8 h; } bb; bb.q = br[ks];
            acc[0] = __builtin_amdgcn_mfma_f32_16x16x32_f16(a0, bb.h, acc[0], 0, 0, 0);
            acc[1] = __builtin_amdgcn_mfma_f32_16x16x32_f16(a1, bb.h, acc[1], 0, 0, 0);
        }
        __builtin_amdgcn_s_setprio(0);
    };

    h8 E0, E1, E2, E3, F0, F1, F2, F3;
    uint4 breg[4], bnext[4];

    GLOAD(0, E0, E1, E2, E3);
    GLOAD(1, F0, F1, F2, F3);
    BLOAD(0, breg);
    GCONSUME(0, 0, E0, E1, E2, E3);
    __syncthreads();

    for (int st = 0; st < NSTAGE; st += 2) {
        // ---- even stage st: compute buf0/breg; prefetch st+2 -> E, B(st+1) ----
        if (st + 2 < NSTAGE) GLOAD(st + 2, E0, E1, E2, E3);
        BLOAD(st + 1, bnext);
        MFMA8(0, breg);
        GCONSUME(st + 1, 1, F0, F1, F2, F3);   // waits st+1 loads (issued 2 stages ago)
        __syncthreads();
        // ---- odd stage st+1: compute buf1/bnext; prefetch st+3 -> F, B(st+2) ----
        if (st + 3 < NSTAGE) GLOAD(st + 3, F0, F1, F2, F3);
        if (st + 2 < NSTAGE) BLOAD(st + 2, breg);
        MFMA8(1, bnext);
        if (st + 2 < NSTAGE) GCONSUME(st + 2, 0, E0, E1, E2, E3);
        __syncthreads();
    }

    // ---- epilogue: col=lane&15 -> co, row=(lane>>4)*4+reg -> px ----
    const int co = n0 * 128 + wv * 16 + pxlo;
    const float bv = db[co];
    float* op = out + ((size_t)(b * COUT + co) << 12) + rowbase;
#pragma unroll
    for (int mi = 0; mi < 2; ++mi) {
        int pxoff = mi * 16 + kslice * 4;
        float4 o;
        o.x = acc[mi][0] + bv;
        o.y = acc[mi][1] + bv;
        o.z = acc[mi][2] + bv;
        o.w = acc[mi][3] + bv;
        *(float4*)&op[pxoff] = o;
    }
}

// ---------------------------------------------------------------------------
extern "C" void kernel_launch(void* const* d_in, const int* in_sizes, int n_in,
                              void* d_out, int out_size, void* d_ws, size_t ws_size,
                              hipStream_t stream)
{
    const float* x  = (const float*)d_in[0];
    const float* ow = (const float*)d_in[1];
    const float* ob = (const float*)d_in[2];
    const float* dw = (const float*)d_in[3];
    const float* db = (const float*)d_in[4];
    float* out = (float*)d_out;

    // ws layout (bytes):
    // opart f32 [2][4][18][4096] = 2359296 | bp f16 1179648 | bow f16 147456 | xT f16 8388608
    char* wsp = (char*)d_ws;
    float*     opart = (float*)wsp;
    _Float16*  bp    = (_Float16*)(wsp + 2359296);
    _Float16*  bow   = (_Float16*)(wsp + 3538944);
    _Float16*  xT    = (_Float16*)(wsp + 3686400);

    hipLaunchKernelGGL(prework_kernel,     dim3(1348), dim3(256), 0, stream, x, ow, dw, xT, bp, bow);
    hipLaunchKernelGGL(offset_mfma_kernel, dim3(512),  dim3(256), 0, stream, xT, bow, opart);
    hipLaunchKernelGGL(dcn_mfma_kernel,    dim3(1024), dim3(512), 0, stream, xT, opart, ob, bp, db, out);
}